// Round 5
// baseline (367.560 us; speedup 1.0000x reference)
//
#include <hip/hip_runtime.h>
#include <hip/hip_bf16.h>

typedef float  float4v __attribute__((ext_vector_type(4)));
typedef short  short8v __attribute__((ext_vector_type(8)));
typedef short  short4v __attribute__((ext_vector_type(4)));
typedef __bf16 bf16x8  __attribute__((ext_vector_type(8)));
typedef float  f32x4   __attribute__((ext_vector_type(4)));

constexpr int NB = 512, T = 64, DIN = 1024, DOUT = 1024;

// ---- workspace layout (bf16-DMA path) ----
constexpr size_t ABF_BYTES = (size_t)NB * T * DIN * 2;   // 67,108,864
constexpr size_t WN_BYTES  = (size_t)DOUT * DIN * 2;     // 2,097,152
constexpr size_t WS_BF16   = ABF_BYTES + WN_BYTES;       // ~69 MB

__device__ __forceinline__ short f2bf_rne(float x) {
    return __builtin_bit_cast(short, __float2bfloat16(x));
}
__device__ __forceinline__ short f2bf_trunc(float x) {   // exact for {0,1}
    return (short)(__builtin_bit_cast(unsigned int, x) >> 16);
}
__device__ __forceinline__ void load_lds_16B(const void* g, void* l) {
    __builtin_amdgcn_global_load_lds(
        (const __attribute__((address_space(1))) unsigned int*)g,
        (__attribute__((address_space(3))) unsigned int*)l, 16, 0, 0);
}

// ---- fused prepass: A fp32{0,1} -> bf16 (trunc, exact) AND Wn = bf16(W*ratio)
constexpr int PREP_A_BLOCKS = NB * T * DIN / 8 / 256;    // 16384
constexpr int PREP_W_BLOCKS = DOUT * DIN / 4 / 256;      // 1024

__global__ void __launch_bounds__(256)
prep_fused(const float* __restrict__ A, short* __restrict__ Abf,
           const float* __restrict__ W, const float* __restrict__ gamma,
           const float* __restrict__ rvar, short* __restrict__ Wn) {
    const int b = blockIdx.x;
    if (b < PREP_A_BLOCKS) {
        int idx = b * 256 + threadIdx.x;                 // 8-elem group
        const float4v* p = (const float4v*)A + (size_t)idx * 2;
        float4v v0 = __builtin_nontemporal_load(p);
        float4v v1 = __builtin_nontemporal_load(p + 1);
        short8v s;
        #pragma unroll
        for (int j = 0; j < 4; j++) {
            s[j]     = f2bf_trunc(v0[j]);
            s[j + 4] = f2bf_trunc(v1[j]);
        }
        *((short8v*)Abf + idx) = s;                      // cached: re-read soon
    } else {
        int idx = (b - PREP_A_BLOCKS) * 256 + threadIdx.x;  // float4 group
        int o = idx >> 8;
        float r = gamma[o] / sqrtf(rvar[o]);
        float4v w = ((const float4v*)W)[idx];
        short4v s;
        #pragma unroll
        for (int j = 0; j < 4; j++) s[j] = f2bf_rne(w[j] * r);
        ((short4v*)Wn)[idx] = s;
    }
}

// standalone fold (used by the ws-small fallback path only)
__global__ void __launch_bounds__(256)
fold_w_kernel(const float* __restrict__ W, const float* __restrict__ gamma,
              const float* __restrict__ rvar, short* __restrict__ Wn) {
    int idx = blockIdx.x * 256 + threadIdx.x;
    int o = idx >> 8;
    float r = gamma[o] / sqrtf(rvar[o]);
    float4v w = ((const float4v*)W)[idx];
    short4v s;
    #pragma unroll
    for (int j = 0; j < 4; j++) s[j] = f2bf_rne(w[j] * r);
    ((short4v*)Wn)[idx] = s;
}

// =====================================================================
// main v5: r0 shell (128x128 tile, 256 thr, 4 waves, BK=64) with
//   (a) B fragments loaded GLOBAL->REG (off the LDS pipe entirely),
//   (b) A double-buffered via global_load_lds (2x16 KB), ONE barrier/tile,
//   (c) panel-major XCD-chunked block swizzle (r4's locality).
//
// Rationale (pipe arithmetic, r0): LDS pipe was ~55 of 90 us/CU
// (64 KB ds_read + 32 KB DMA-write per block-tile). B fragments are
// contiguous 16 B runs in global Wn -> per-instr 16 rows x 64 B
// segments, L2-resident (Wn = 2 MB). Removing B from LDS halves the
// dominant pipe; A-stage latency + barrier skew hidden by 12 waves/CU
// of cross-block TLP (the mechanism that made r0 fastest).
//
// Waits: per tile, B-reg loads issue FIRST, then A-stage(t+1): the
// compiler's B-wait is vmcnt(4), keeping the stage in flight through
// the MFMAs. At tile bottom only the stage is outstanding, so plain
// __syncthreads() (vmcnt 0 + barrier) is exactly the required wait --
// no manual counted vmcnt, divergence-safe.
// =====================================================================
constexpr int BM = 128, BN = 128, BK = 64;
constexpr int NT = DIN / BK;                      // 16
constexpr int ABUF = BM * BK * 2;                 // 16384 B per A buffer

__global__ void __launch_bounds__(256, 3)
snn_gemm_if_breg(const short* __restrict__ Abf,  // (N*T, DIN) bf16 {0,1}
                 const short* __restrict__ Wn,   // (DOUT, DIN) bf16, folded
                 const float* __restrict__ bias, const float* __restrict__ gamma,
                 const float* __restrict__ beta, const float* __restrict__ rmean,
                 const float* __restrict__ rvar, float* __restrict__ out) {
    __shared__ __align__(16) char sm[2 * ABUF];   // A dbuf; potS (32 KB) alias
    __shared__ float bstepS[BN];

    const int tid = threadIdx.x;
    // panel-major XCD chunking: 2048 blocks; each XCD gets 256 contiguous
    // works; the 8 N-blocks of one A panel are adjacent -> same-XCD L2 hit.
    const int b     = blockIdx.x;
    const int work  = (b & 7) * 256 + (b >> 3);
    const int panel = work >> 3;                  // sample pair 0..255
    const int oB    = (work & 7) * BN;            // N block

    if (tid < BN) {
        int o = oB + tid;
        float r = gamma[o] / sqrtf(rvar[o]);
        bstepS[tid] = ((bias[o] - rmean[o]) * r + beta[o]) * (1.0f / 64.0f);
    }

    const int lane = tid & 63;
    const int wv   = tid >> 6;
    const int wr   = wv & 1;                      // M 64-half
    const int wc   = wv >> 1;                     // N 64-half
    const int l15  = lane & 15;
    const int quad = lane >> 4;

    // ---- A staging (r0-proven): slot s holds row=s>>3, chunk=(s&7)^(row&7)
    int srcOff[4];
    #pragma unroll
    for (int i = 0; i < 4; i++) {
        int s   = i * 256 + tid;
        int row = s >> 3;
        int ck  = (s & 7) ^ (row & 7);
        srcOff[i] = (row * DIN + ck * 8) * 2;     // bytes
    }
    // A fragment LDS offsets (r0-proven swizzle)
    int aOff[4][2];
    #pragma unroll
    for (int i = 0; i < 4; i++) {
        int ra = wr * 64 + i * 16 + l15;
        #pragma unroll
        for (int ks = 0; ks < 2; ks++) {
            int c = ks * 4 + quad;
            aOff[i][ks] = (ra * 8 + (c ^ (ra & 7))) * 16;
        }
    }

    // ---- B fragment global bases: frag(ni,ks) = 16 contiguous bytes at
    // Wn[oB + wc*64 + ni*16 + l15][kb + ks*32 + quad*8]
    const short* gBf[4];
    #pragma unroll
    for (int ni = 0; ni < 4; ni++)
        gBf[ni] = Wn + (size_t)(oB + wc * 64 + ni * 16 + l15) * DIN + quad * 8;

    f32x4 acc[4][4] = {};
    const char* Ab = (const char*)(Abf + (size_t)panel * BM * DIN);
    char* As0 = sm;
    char* As1 = sm + ABUF;

    // prologue: stage tile 0 into buf0
    #pragma unroll
    for (int i = 0; i < 4; i++)
        load_lds_16B(Ab + srcOff[i], As0 + (i * 256 + tid) * 16);
    __syncthreads();

    #pragma unroll 1
    for (int t = 0; t < NT; ++t) {
        const int kb = t * BK;
        // 1) B fragments -> regs (issued first: their wait = vmcnt(4),
        //    keeping the A-stage below in flight through the MFMAs)
        short8v bvr[4][2];
        #pragma unroll
        for (int ni = 0; ni < 4; ni++)
            #pragma unroll
            for (int ks = 0; ks < 2; ks++)
                bvr[ni][ks] = *(const short8v*)(gBf[ni] + kb + ks * 32);
        __builtin_amdgcn_sched_barrier(0);        // pin: B issued before stage
        // 2) stage A(t+1) into the other buffer
        if (t < NT - 1) {
            const int kbB = (kb + BK) * 2;
            #pragma unroll
            for (int i = 0; i < 4; i++)
                load_lds_16B(Ab + srcOff[i] + kbB, As1 + (i * 256 + tid) * 16);
        }
        // 3) compute tile t from As0
        #pragma unroll
        for (int ks = 0; ks < 2; ks++) {
            bf16x8 af[4];
            #pragma unroll
            for (int i = 0; i < 4; i++)
                af[i] = __builtin_bit_cast(bf16x8,
                    *(const short8v*)(As0 + aOff[i][ks]));
            #pragma unroll
            for (int mi = 0; mi < 4; mi++)
                #pragma unroll
                for (int ni = 0; ni < 4; ni++)
                    acc[mi][ni] = __builtin_amdgcn_mfma_f32_16x16x32_bf16(
                        af[mi], __builtin_bit_cast(bf16x8, bvr[ni][ks]),
                        acc[mi][ni], 0, 0, 0);
        }
        // 4) bottom: only the A-stage is outstanding -> __syncthreads'
        //    vmcnt(0)+barrier is exactly "stage landed for all waves"
        __syncthreads();
        char* tmp = As0; As0 = As1; As1 = tmp;
    }

    // ---- epilogue (r0-proven): acc -> potS (quad-XOR banks), IF scan ----
    float* potS = (float*)sm;                     // 64 x 128 fp32 = 32 KB
    #pragma unroll 1
    for (int s = 0; s < 2; s++) {
        if (wr == s) {
            #pragma unroll
            for (int mi = 0; mi < 4; mi++)
                #pragma unroll
                for (int ni = 0; ni < 4; ni++)
                    #pragma unroll
                    for (int r = 0; r < 4; r++) {
                        int row = mi * 16 + quad * 4 + r;
                        int col = (wc * 64 + ni * 16 + l15) ^ (quad << 3);
                        potS[row * BN + col] = acc[mi][ni][r];
                    }
        }
        __syncthreads();
        if (tid < BN) {
            int n = panel * 2 + s;
            float pot = 0.f, cnt = 0.f;
            const float bst = bstepS[tid];
            float* so = out + (size_t)n * T * DOUT + oB + tid;
            for (int t = 0; t < T; t++) {
                pot += potS[t * BN + (tid ^ (((t >> 2) & 3) << 3))] + bst;
                float spk = (pot >= 1.0f) ? 1.0f : 0.0f;
                pot -= spk;
                cnt += spk;
                __builtin_nontemporal_store(spk, so + (size_t)t * DOUT);
            }
            __builtin_nontemporal_store(
                cnt, out + (size_t)NB * T * DOUT + (size_t)n * DOUT + oB + tid);
        }
        __syncthreads();
    }
}

// ===================== fallback (round-2 proven path) =====================

constexpr int LDA_F = 72;
constexpr int A_BYTES_F = BM * LDA_F * 2;
constexpr int SMEM_F = A_BYTES_F + BN * BK * 2;

template <bool PREFOLD>
__global__ void __launch_bounds__(256)
snn_gemm_if(const float* __restrict__ A, const float* __restrict__ W,
            const short* __restrict__ Wn,
            const float* __restrict__ bias, const float* __restrict__ gamma,
            const float* __restrict__ beta, const float* __restrict__ rmean,
            const float* __restrict__ rvar, float* __restrict__ out) {
    __shared__ __align__(16) char smem[SMEM_F];
    __shared__ float ratioS[BN];
    __shared__ float bstepS[BN];
    short* AsS  = (short*)smem;
    short* BsS  = (short*)(smem + A_BYTES_F);
    float* potS = (float*)smem;

    const int tid   = threadIdx.x;
    const int by    = blockIdx.y;
    const int oBase = blockIdx.x * BN;

    if (tid < BN) {
        int o = oBase + tid;
        float r = gamma[o] / sqrtf(rvar[o]);
        ratioS[tid] = r;
        bstepS[tid] = ((bias[o] - rmean[o]) * r + beta[o]) * (1.0f / 64.0f);
    }
    __syncthreads();

    const int lane = tid & 63;
    const int wv   = tid >> 6;
    const int wr   = wv & 1;
    const int wc   = wv >> 1;
    const int l15  = lane & 15;
    const int quad = lane >> 4;

    f32x4 acc[4][4] = {};
    const float* Ab = A + (size_t)by * BM * DIN;

    for (int kb = 0; kb < DIN; kb += BK) {
        float4v av[4][2];
        #pragma unroll
        for (int i = 0; i < 4; i++) {
            int g = i * 256 + tid;
            int r = g >> 3, k8 = g & 7;
            const float4v* p = (const float4v*)(Ab + (size_t)r * DIN + kb + k8 * 8);
            av[i][0] = p[0];
            av[i][1] = p[1];
        }
        float4v bv[4][2];
        if constexpr (!PREFOLD) {
            #pragma unroll
            for (int i = 0; i < 4; i++) {
                int slot = i * 256 + tid;
                int r = slot >> 3, k8 = (slot & 7) ^ (r & 7);
                const float4v* p = (const float4v*)(W + (size_t)(oBase + r) * DIN + kb + k8 * 8);
                bv[i][0] = p[0];
                bv[i][1] = p[1];
            }
        }
        __syncthreads();

        if constexpr (PREFOLD) {
            #pragma unroll
            for (int i = 0; i < 4; i++) {
                int slot = i * 256 + tid;
                int r = slot >> 3, k8 = (slot & 7) ^ (r & 7);
                load_lds_16B(Wn + (size_t)(oBase + r) * DIN + kb + k8 * 8,
                             BsS + (size_t)slot * 8);
            }
        } else {
            #pragma unroll
            for (int i = 0; i < 4; i++) {
                int slot = i * 256 + tid;
                int r = slot >> 3;
                float rt = ratioS[r];
                short8v s;
                #pragma unroll
                for (int j = 0; j < 4; j++) {
                    s[j]     = f2bf_rne(bv[i][0][j] * rt);
                    s[j + 4] = f2bf_rne(bv[i][1][j] * rt);
                }
                *(short8v*)(BsS + (size_t)slot * 8) = s;
            }
        }
        #pragma unroll
        for (int i = 0; i < 4; i++) {
            int g = i * 256 + tid;
            int r = g >> 3, k8 = g & 7;
            short8v s;
            #pragma unroll
            for (int j = 0; j < 4; j++) {
                s[j]     = f2bf_trunc(av[i][0][j]);
                s[j + 4] = f2bf_trunc(av[i][1][j]);
            }
            *(short8v*)(&AsS[r * LDA_F + k8 * 8]) = s;
        }
        __syncthreads();

        #pragma unroll
        for (int ks = 0; ks < 2; ks++) {
            bf16x8 af[4], bfv[4];
            #pragma unroll
            for (int mi = 0; mi < 4; mi++)
                af[mi] = __builtin_bit_cast(bf16x8,
                    *(const short8v*)(&AsS[(wr * 64 + mi * 16 + l15) * LDA_F + ks * 32 + quad * 8]));
            #pragma unroll
            for (int ni = 0; ni < 4; ni++) {
                int row  = wc * 64 + ni * 16 + l15;
                int slot = row * 8 + ((ks * 4 + quad) ^ (l15 & 7));
                bfv[ni] = __builtin_bit_cast(bf16x8, *(const short8v*)(BsS + (size_t)slot * 8));
            }
            #pragma unroll
            for (int mi = 0; mi < 4; mi++)
                #pragma unroll
                for (int ni = 0; ni < 4; ni++)
                    acc[mi][ni] = __builtin_amdgcn_mfma_f32_16x16x32_bf16(
                        af[mi], bfv[ni], acc[mi][ni], 0, 0, 0);
        }
    }

    __syncthreads();

    #pragma unroll 1
    for (int s = 0; s < 2; s++) {
        if (wr == s) {
            #pragma unroll
            for (int mi = 0; mi < 4; mi++)
                #pragma unroll
                for (int ni = 0; ni < 4; ni++)
                    #pragma unroll
                    for (int r = 0; r < 4; r++)
                        potS[(mi * 16 + quad * 4 + r) * BN + wc * 64 + ni * 16 + l15] =
                            acc[mi][ni][r];
        }
        __syncthreads();
        if (tid < BN) {
            int n = by * 2 + s;
            float pot = 0.f, cnt = 0.f;
            const float bst = bstepS[tid];
            float* so = out + (size_t)n * T * DOUT + oBase + tid;
            for (int t = 0; t < T; t++) {
                pot += potS[t * BN + tid] + bst;
                float spk = (pot >= 1.0f) ? 1.0f : 0.0f;
                pot -= spk;
                cnt += spk;
                so[(size_t)t * DOUT] = spk;
            }
            out[(size_t)NB * T * DOUT + (size_t)n * DOUT + oBase + tid] = cnt;
        }
        __syncthreads();
    }
}

extern "C" void kernel_launch(void* const* d_in, const int* in_sizes, int n_in,
                              void* d_out, int out_size, void* d_ws, size_t ws_size,
                              hipStream_t stream) {
    const float* A     = (const float*)d_in[0];
    // d_in[1] (input_features_sc) feeds only the un-returned ANN path — dead.
    const float* W     = (const float*)d_in[2];
    const float* bias  = (const float*)d_in[3];
    const float* gamma = (const float*)d_in[4];
    const float* beta  = (const float*)d_in[5];
    const float* rmean = (const float*)d_in[6];
    const float* rvar  = (const float*)d_in[7];
    float* out = (float*)d_out;

    if (d_ws != nullptr && ws_size >= WS_BF16) {
        short* Abf = (short*)d_ws;
        short* Wn  = (short*)((char*)d_ws + ABF_BYTES);
        prep_fused<<<PREP_A_BLOCKS + PREP_W_BLOCKS, 256, 0, stream>>>(
            A, Abf, W, gamma, rvar, Wn);
        snn_gemm_if_breg<<<dim3(2048), 256, 0, stream>>>(Abf, Wn, bias, gamma,
                                                         beta, rmean, rvar, out);
    } else if (d_ws != nullptr && ws_size >= WN_BYTES) {
        short* Wn = (short*)d_ws;
        fold_w_kernel<<<DOUT * DIN / 4 / 256, 256, 0, stream>>>(W, gamma, rvar, Wn);
        dim3 grid(DOUT / BN, NB / 2);
        snn_gemm_if<true><<<grid, 256, 0, stream>>>(A, W, Wn, bias, gamma, beta,
                                                    rmean, rvar, out);
    } else {
        dim3 grid(DOUT / BN, NB / 2);
        snn_gemm_if<false><<<grid, 256, 0, stream>>>(A, W, nullptr, bias, gamma, beta,
                                                     rmean, rvar, out);
    }
}

// Round 6
// 300.007 us; speedup vs baseline: 1.2252x; 1.2252x over previous
//
#include <hip/hip_runtime.h>
#include <hip/hip_bf16.h>

typedef float  float4v __attribute__((ext_vector_type(4)));
typedef short  short8v __attribute__((ext_vector_type(8)));
typedef short  short4v __attribute__((ext_vector_type(4)));
typedef __bf16 bf16x8  __attribute__((ext_vector_type(8)));
typedef float  f32x4   __attribute__((ext_vector_type(4)));

constexpr int NB = 512, T = 64, DIN = 1024, DOUT = 1024;

// ---- workspace layout (bf16-DMA path) ----
constexpr size_t ABF_BYTES = (size_t)NB * T * DIN * 2;   // 67,108,864
constexpr size_t WN_BYTES  = (size_t)DOUT * DIN * 2;     // 2,097,152
constexpr size_t WS_BF16   = ABF_BYTES + WN_BYTES;       // ~69 MB

__device__ __forceinline__ short f2bf_rne(float x) {
    return __builtin_bit_cast(short, __float2bfloat16(x));
}
__device__ __forceinline__ short f2bf_trunc(float x) {   // exact for {0,1}
    return (short)(__builtin_bit_cast(unsigned int, x) >> 16);
}
__device__ __forceinline__ void load_lds_16B(const void* g, void* l) {
    __builtin_amdgcn_global_load_lds(
        (const __attribute__((address_space(1))) unsigned int*)g,
        (__attribute__((address_space(3))) unsigned int*)l, 16, 0, 0);
}

// ---- fused prepass: A fp32{0,1} -> bf16 (trunc, exact) AND Wn = bf16(W*ratio)
constexpr int PREP_A_BLOCKS = NB * T * DIN / 8 / 256;    // 16384
constexpr int PREP_W_BLOCKS = DOUT * DIN / 4 / 256;      // 1024

__global__ void __launch_bounds__(256)
prep_fused(const float* __restrict__ A, short* __restrict__ Abf,
           const float* __restrict__ W, const float* __restrict__ gamma,
           const float* __restrict__ rvar, short* __restrict__ Wn) {
    const int b = blockIdx.x;
    if (b < PREP_A_BLOCKS) {
        int idx = b * 256 + threadIdx.x;                 // 8-elem group
        const float4v* p = (const float4v*)A + (size_t)idx * 2;
        float4v v0 = __builtin_nontemporal_load(p);
        float4v v1 = __builtin_nontemporal_load(p + 1);
        short8v s;
        #pragma unroll
        for (int j = 0; j < 4; j++) {
            s[j]     = f2bf_trunc(v0[j]);
            s[j + 4] = f2bf_trunc(v1[j]);
        }
        *((short8v*)Abf + idx) = s;                      // cached: re-read soon
    } else {
        int idx = (b - PREP_A_BLOCKS) * 256 + threadIdx.x;  // float4 group
        int o = idx >> 8;
        float r = gamma[o] / sqrtf(rvar[o]);
        float4v w = ((const float4v*)W)[idx];
        short4v s;
        #pragma unroll
        for (int j = 0; j < 4; j++) s[j] = f2bf_rne(w[j] * r);
        ((short4v*)Wn)[idx] = s;
    }
}

// standalone fold (used by the ws-small fallback path only)
__global__ void __launch_bounds__(256)
fold_w_kernel(const float* __restrict__ W, const float* __restrict__ gamma,
              const float* __restrict__ rvar, short* __restrict__ Wn) {
    int idx = blockIdx.x * 256 + threadIdx.x;
    int o = idx >> 8;
    float r = gamma[o] / sqrtf(rvar[o]);
    float4v w = ((const float4v*)W)[idx];
    short4v s;
    #pragma unroll
    for (int j = 0; j < 4; j++) s[j] = f2bf_rne(w[j] * r);
    ((short4v*)Wn)[idx] = s;
}

// =====================================================================
// main v6: faithful m201 8-phase port. 256x256 tile, BK=64, 512 thr =
// 8 waves (2M x 4N), wave-tile 128x64, acc[8][4].
//
// LDS: 2 dbuf x 4 units x 16 KB = 128 KB. Unit = half-tile:
//   A0 = A rows 0-127, A1 = rows 128-255 (128 x 64K bf16),
//   B0 = W rows oB..+127, B1 = +128. buf[kt&1] holds K-tile kt.
//
// Per K-tile g: 4 phases, phase q computes quadrant (mh=q>>1, nh=q&1):
//   { ds_read subtile (q0: A-mh0 8 + B-nh0 4; q1: B-nh1 4; q2: A-mh1 8);
//     stage ONE unit (2 gload_lds/thread);
//     s_barrier; setprio(1); 16 MFMA; setprio(0); s_barrier }
//
// Staging schedule (intra-buffer WAR-safe: B units of buf[g&1] are fully
// read after q1, A units after q2):
//   q0: A0(g+1) -> buf[(g+1)&1]   (that buf's A last read at (g-1,q2))
//   q1: A1(g+1) -> buf[(g+1)&1]
//   q2: B0(g+2) -> buf[g&1]       (current buf's B last read at q1)
//   q3: B1(g+2) -> buf[g&1]
// FIFO vmcnt, 2 loads/wave per stage. Checkpoint ONCE per K-tile, at q3
// after MFMA: kt g+1's units were staged at (g-1,q2),(g-1,q3),(g,q0),
// (g,q1); stages after them = (g,q2),(g,q3) = 2 units = 4 loads
// => s_waitcnt vmcnt(4) + s_barrier guarantees kt g+1 landed for ALL
// waves before (g+1,q0) ds_reads. Last checkpoint (g==14) uses vmcnt(0).
// Prologue: stage kt0's 4 units then kt1's 4; vmcnt(8) lands kt0.
//
// Swizzle (r0-proven, both-sides involution): within a unit, row r
// chunk c (16 B) stored at linear chunk c^(r&7); DMA dest linear,
// global source pre-swizzled; ds_read applies the same XOR. 2 lanes/bank.
// =====================================================================
constexpr int BM2 = 256, BN2 = 256, BK2 = 64;
constexpr int NKT = DIN / BK2;                    // 16 K-tiles
constexpr int UNIT = 16384;                       // 128 x 64 bf16
constexpr int DBUF = 4 * UNIT;                    // 64 KB per buffer

__global__ void __launch_bounds__(512, 2)
snn_gemm_if_8ph(const short* __restrict__ Abf,  // (N*T, DIN) bf16 {0,1}
                const short* __restrict__ Wn,   // (DOUT, DIN) bf16, folded
                const float* __restrict__ bias, const float* __restrict__ gamma,
                const float* __restrict__ beta, const float* __restrict__ rmean,
                const float* __restrict__ rvar, float* __restrict__ out) {
    __shared__ __align__(16) char sm[2 * DBUF];   // 128 KB; potS aliases
    __shared__ float bstepS[BN2];

    const int tid = threadIdx.x;
    // XCD-chunked swizzle: 512 blocks, 64 contiguous works per XCD;
    // 4 consecutive works share an A panel.
    const int work = (blockIdx.x & 7) * 64 + (blockIdx.x >> 3);
    const int oB = (work & 3) * BN2;
    const int rg = work >> 2;                     // A rows rg*256.., samples rg*4..

    if (tid < BN2) {
        int o = oB + tid;
        float r = gamma[o] / sqrtf(rvar[o]);
        bstepS[tid] = ((bias[o] - rmean[o]) * r + beta[o]) * (1.0f / 64.0f);
    }
    // retire bstep loads so vmcnt accounting below is exact
    asm volatile("s_waitcnt vmcnt(0)" ::: "memory");
    __builtin_amdgcn_sched_barrier(0);

    const int lane = tid & 63;
    const int wv   = tid >> 6;                    // 0..7
    const int wr   = wv >> 2;                     // 0..1: M-half (128 rows)
    const int wc   = wv & 3;                      // 0..3: N 64-col band
    const int l15  = lane & 15;
    const int quad = lane >> 4;

    // per-lane ds_read sub-offsets (chunk swizzle c ^= row&7; row&7==lane&7)
    const int D0 = l15 * 128 + ((quad ^ (lane & 7)) * 16);        // ks=0
    const int D1 = l15 * 128 + (((4 + quad) ^ (lane & 7)) * 16);  // ks=1

    // staging: thread covers unit slots tid and tid+512.
    // slot s: row=s>>3, linear chunk s&7 <- global chunk (s&7)^(row&7).
    const int row0 = tid >> 3,         ck0 = (tid & 7) ^ (row0 & 7);
    const int row1 = (512 + tid) >> 3, ck1 = ((512 + tid) & 7) ^ (row1 & 7);
    const int srcOff0 = (row0 * DIN + ck0 * 8) * 2;   // bytes
    const int srcOff1 = (row1 * DIN + ck1 * 8) * 2;

    const char* aU[2] = { (const char*)(Abf + (size_t)rg * BM2 * DIN),
                          (const char*)(Abf + (size_t)(rg * BM2 + 128) * DIN) };
    const char* bU[2] = { (const char*)(Wn + (size_t)oB * DIN),
                          (const char*)(Wn + (size_t)(oB + 128) * DIN) };

    auto STAGE = [&](const char* uPtr, int ktB, int dstB) {
        load_lds_16B(uPtr + srcOff0 + ktB, sm + dstB + tid * 16);
        load_lds_16B(uPtr + srcOff1 + ktB, sm + dstB + 8192 + tid * 16);
    };
    auto LD8 = [&](const char* p) {
        return __builtin_bit_cast(bf16x8, *(const short8v*)p);
    };

    f32x4 acc[8][4] = {};
    bf16x8 af[4][2], bf0[2][2], bf1[2][2];

    // within-buffer read bases for this wave
    const int aBase = wr * UNIT;                          // unit A{wr}
    const int bBase = 2 * UNIT + (wc >> 1) * UNIT + (wc & 1) * 8192;

    // ---- prologue: kt0 (buf0) then kt1 (buf1); land kt0 ----
    STAGE(aU[0], 0, 0);           STAGE(aU[1], 0, UNIT);
    STAGE(bU[0], 0, 2 * UNIT);    STAGE(bU[1], 0, 3 * UNIT);
    STAGE(aU[0], 128, DBUF);      STAGE(aU[1], 128, DBUF + UNIT);
    STAGE(bU[0], 128, DBUF + 2 * UNIT);
    STAGE(bU[1], 128, DBUF + 3 * UNIT);
    asm volatile("s_waitcnt vmcnt(8)" ::: "memory");      // kt0's 8 loads done
    __builtin_amdgcn_sched_barrier(0);
    __builtin_amdgcn_s_barrier();
    __builtin_amdgcn_sched_barrier(0);

    #pragma unroll 1
    for (int g = 0; g < NKT; ++g) {
        const int bufB  = (g & 1) ? DBUF : 0;
        const int obufB = (g & 1) ? 0 : DBUF;             // buf[(g+1)&1]
        const int ktB1  = (g + 1) * 128;                  // A-stage K offset
        const int ktB2  = (g + 2) * 128;                  // B-stage K offset
        const char* pA = sm + bufB + aBase;
        const char* pB = sm + bufB + bBase;
        const bool stA = (g >= 1) && (g <= NKT - 2);      // kt g+1 A units
        const bool stB = (g <= NKT - 3);                  // kt g+2 B units

        // ================= q0: quadrant (mh=0, nh=0) =================
        #pragma unroll
        for (int i = 0; i < 4; i++) {                     // A-mh0: 8 reads
            af[i][0] = LD8(pA + i * 2048 + D0);
            af[i][1] = LD8(pA + i * 2048 + D1);
        }
        #pragma unroll
        for (int j = 0; j < 2; j++) {                     // B-nh0: 4 reads
            bf0[j][0] = LD8(pB + j * 2048 + D0);
            bf0[j][1] = LD8(pB + j * 2048 + D1);
        }
        if (stA) STAGE(aU[0], ktB1, obufB);               // A0(g+1)
        __builtin_amdgcn_s_barrier();
        __builtin_amdgcn_s_setprio(1);
        #pragma unroll
        for (int mi = 0; mi < 4; mi++)
            #pragma unroll
            for (int ni = 0; ni < 2; ni++)
                #pragma unroll
                for (int ks = 0; ks < 2; ks++)
                    acc[mi][ni] = __builtin_amdgcn_mfma_f32_16x16x32_bf16(
                        af[mi][ks], bf0[ni][ks], acc[mi][ni], 0, 0, 0);
        __builtin_amdgcn_s_setprio(0);
        __builtin_amdgcn_s_barrier();

        // ================= q1: quadrant (mh=0, nh=1) =================
        #pragma unroll
        for (int j = 0; j < 2; j++) {                     // B-nh1: 4 reads
            bf1[j][0] = LD8(pB + 4096 + j * 2048 + D0);
            bf1[j][1] = LD8(pB + 4096 + j * 2048 + D1);
        }
        if (stA) STAGE(aU[1], ktB1, obufB + UNIT);        // A1(g+1)
        __builtin_amdgcn_s_barrier();
        __builtin_amdgcn_s_setprio(1);
        #pragma unroll
        for (int mi = 0; mi < 4; mi++)
            #pragma unroll
            for (int ni = 0; ni < 2; ni++)
                #pragma unroll
                for (int ks = 0; ks < 2; ks++)
                    acc[mi][2 + ni] = __builtin_amdgcn_mfma_f32_16x16x32_bf16(
                        af[mi][ks], bf1[ni][ks], acc[mi][2 + ni], 0, 0, 0);
        __builtin_amdgcn_s_setprio(0);
        __builtin_amdgcn_s_barrier();

        // ================= q2: quadrant (mh=1, nh=0) =================
        #pragma unroll
        for (int i = 0; i < 4; i++) {                     // A-mh1: 8 reads
            af[i][0] = LD8(pA + 8192 + i * 2048 + D0);
            af[i][1] = LD8(pA + 8192 + i * 2048 + D1);
        }
        if (stB) STAGE(bU[0], ktB2, bufB + 2 * UNIT);     // B0(g+2)
        __builtin_amdgcn_s_barrier();
        __builtin_amdgcn_s_setprio(1);
        #pragma unroll
        for (int mi = 0; mi < 4; mi++)
            #pragma unroll
            for (int ni = 0; ni < 2; ni++)
                #pragma unroll
                for (int ks = 0; ks < 2; ks++)
                    acc[4 + mi][ni] = __builtin_amdgcn_mfma_f32_16x16x32_bf16(
                        af[mi][ks], bf0[ni][ks], acc[4 + mi][ni], 0, 0, 0);
        __builtin_amdgcn_s_setprio(0);
        __builtin_amdgcn_s_barrier();

        // ================= q3: quadrant (mh=1, nh=1) =================
        if (stB) STAGE(bU[1], ktB2, bufB + 3 * UNIT);     // B1(g+2)
        __builtin_amdgcn_s_barrier();
        __builtin_amdgcn_s_setprio(1);
        #pragma unroll
        for (int mi = 0; mi < 4; mi++)
            #pragma unroll
            for (int ni = 0; ni < 2; ni++)
                #pragma unroll
                for (int ks = 0; ks < 2; ks++)
                    acc[4 + mi][2 + ni] = __builtin_amdgcn_mfma_f32_16x16x32_bf16(
                        af[mi][ks], bf1[ni][ks], acc[4 + mi][2 + ni], 0, 0, 0);
        __builtin_amdgcn_s_setprio(0);
        // ---- once-per-K-tile checkpoint: kt g+1 fully landed ----
        if (g <= NKT - 3) {
            asm volatile("s_waitcnt vmcnt(4)" ::: "memory");
        } else if (g == NKT - 2) {
            asm volatile("s_waitcnt vmcnt(0)" ::: "memory");
        }
        __builtin_amdgcn_sched_barrier(0);
        __builtin_amdgcn_s_barrier();
        __builtin_amdgcn_sched_barrier(0);
    }

    __syncthreads();                              // full drain; potS aliases

    // ---- epilogue (r2-verified): 2 rounds of 2 samples ----
    float* potS = (float*)sm;                     // 128 x 256 fp32 = 128 KB
    #pragma unroll 1
    for (int rd = 0; rd < 2; ++rd) {
        if (wr == rd) {                           // this wave's 128 rows
            #pragma unroll
            for (int mi = 0; mi < 8; mi++)
                #pragma unroll
                for (int ni = 0; ni < 4; ni++)
                    #pragma unroll
                    for (int r = 0; r < 4; r++) {
                        int rowl = mi * 16 + quad * 4 + r;
                        int col  = (wc * 64 + ni * 16 + l15) ^ (quad << 3);
                        potS[rowl * BN2 + col] = acc[mi][ni][r];
                    }
        }
        __syncthreads();
        {
            int sl = tid >> 8;                    // 0..1: sample within round
            int c  = tid & 255;
            int n  = rg * 4 + rd * 2 + sl;
            float pot = 0.f, cnt = 0.f;
            const float bst = bstepS[c];
            float* so = out + (size_t)n * T * DOUT + oB + c;
            for (int tt = 0; tt < T; tt++) {
                pot += potS[(sl * 64 + tt) * BN2 + (c ^ (((tt >> 2) & 3) << 3))] + bst;
                float spk = (pot >= 1.0f) ? 1.0f : 0.0f;
                pot -= spk;
                cnt += spk;
                __builtin_nontemporal_store(spk, so + (size_t)tt * DOUT);
            }
            __builtin_nontemporal_store(
                cnt, out + (size_t)NB * T * DOUT + (size_t)n * DOUT + oB + c);
        }
        __syncthreads();
    }
}

// ===================== fallback (round-2 proven path) =====================

constexpr int BM = 128, BN = 128, BK = 64;
constexpr int LDA_F = 72;
constexpr int A_BYTES_F = BM * LDA_F * 2;
constexpr int SMEM_F = A_BYTES_F + BN * BK * 2;

template <bool PREFOLD>
__global__ void __launch_bounds__(256)
snn_gemm_if(const float* __restrict__ A, const float* __restrict__ W,
            const short* __restrict__ Wn,
            const float* __restrict__ bias, const float* __restrict__ gamma,
            const float* __restrict__ beta, const float* __restrict__ rmean,
            const float* __restrict__ rvar, float* __restrict__ out) {
    __shared__ __align__(16) char smem[SMEM_F];
    __shared__ float ratioS[BN];
    __shared__ float bstepS[BN];
    short* AsS  = (short*)smem;
    short* BsS  = (short*)(smem + A_BYTES_F);
    float* potS = (float*)smem;

    const int tid   = threadIdx.x;
    const int by    = blockIdx.y;
    const int oBase = blockIdx.x * BN;

    if (tid < BN) {
        int o = oBase + tid;
        float r = gamma[o] / sqrtf(rvar[o]);
        ratioS[tid] = r;
        bstepS[tid] = ((bias[o] - rmean[o]) * r + beta[o]) * (1.0f / 64.0f);
    }
    __syncthreads();

    const int lane = tid & 63;
    const int wv   = tid >> 6;
    const int wr   = wv & 1;
    const int wc   = wv >> 1;
    const int l15  = lane & 15;
    const int quad = lane >> 4;

    f32x4 acc[4][4] = {};
    const float* Ab = A + (size_t)by * BM * DIN;

    for (int kb = 0; kb < DIN; kb += BK) {
        float4v av[4][2];
        #pragma unroll
        for (int i = 0; i < 4; i++) {
            int g = i * 256 + tid;
            int r = g >> 3, k8 = g & 7;
            const float4v* p = (const float4v*)(Ab + (size_t)r * DIN + kb + k8 * 8);
            av[i][0] = p[0];
            av[i][1] = p[1];
        }
        float4v bv[4][2];
        if constexpr (!PREFOLD) {
            #pragma unroll
            for (int i = 0; i < 4; i++) {
                int slot = i * 256 + tid;
                int r = slot >> 3, k8 = (slot & 7) ^ (r & 7);
                const float4v* p = (const float4v*)(W + (size_t)(oBase + r) * DIN + kb + k8 * 8);
                bv[i][0] = p[0];
                bv[i][1] = p[1];
            }
        }
        __syncthreads();

        if constexpr (PREFOLD) {
            #pragma unroll
            for (int i = 0; i < 4; i++) {
                int slot = i * 256 + tid;
                int r = slot >> 3, k8 = (slot & 7) ^ (r & 7);
                load_lds_16B(Wn + (size_t)(oBase + r) * DIN + kb + k8 * 8,
                             BsS + (size_t)slot * 8);
            }
        } else {
            #pragma unroll
            for (int i = 0; i < 4; i++) {
                int slot = i * 256 + tid;
                int r = slot >> 3;
                float rt = ratioS[r];
                short8v s;
                #pragma unroll
                for (int j = 0; j < 4; j++) {
                    s[j]     = f2bf_rne(bv[i][0][j] * rt);
                    s[j + 4] = f2bf_rne(bv[i][1][j] * rt);
                }
                *(short8v*)(BsS + (size_t)slot * 8) = s;
            }
        }
        #pragma unroll
        for (int i = 0; i < 4; i++) {
            int g = i * 256 + tid;
            int r = g >> 3, k8 = g & 7;
            short8v s;
            #pragma unroll
            for (int j = 0; j < 4; j++) {
                s[j]     = f2bf_trunc(av[i][0][j]);
                s[j + 4] = f2bf_trunc(av[i][1][j]);
            }
            *(short8v*)(&AsS[r * LDA_F + k8 * 8]) = s;
        }
        __syncthreads();

        #pragma unroll
        for (int ks = 0; ks < 2; ks++) {
            bf16x8 af[4], bfv[4];
            #pragma unroll
            for (int mi = 0; mi < 4; mi++)
                af[mi] = __builtin_bit_cast(bf16x8,
                    *(const short8v*)(&AsS[(wr * 64 + mi * 16 + l15) * LDA_F + ks * 32 + quad * 8]));
            #pragma unroll
            for (int ni = 0; ni < 4; ni++) {
                int row  = wc * 64 + ni * 16 + l15;
                int slot = row * 8 + ((ks * 4 + quad) ^ (l15 & 7));
                bfv[ni] = __builtin_bit_cast(bf16x8, *(const short8v*)(BsS + (size_t)slot * 8));
            }
            #pragma unroll
            for (int mi = 0; mi < 4; mi++)
                #pragma unroll
                for (int ni = 0; ni < 4; ni++)
                    acc[mi][ni] = __builtin_amdgcn_mfma_f32_16x16x32_bf16(
                        af[mi], bfv[ni], acc[mi][ni], 0, 0, 0);
        }
    }

    __syncthreads();

    #pragma unroll 1
    for (int s = 0; s < 2; s++) {
        if (wr == s) {
            #pragma unroll
            for (int mi = 0; mi < 4; mi++)
                #pragma unroll
                for (int ni = 0; ni < 4; ni++)
                    #pragma unroll
                    for (int r = 0; r < 4; r++)
                        potS[(mi * 16 + quad * 4 + r) * BN + wc * 64 + ni * 16 + l15] =
                            acc[mi][ni][r];
        }
        __syncthreads();
        if (tid < BN) {
            int n = by * 2 + s;
            float pot = 0.f, cnt = 0.f;
            const float bst = bstepS[tid];
            float* so = out + (size_t)n * T * DOUT + oBase + tid;
            for (int t = 0; t < T; t++) {
                pot += potS[t * BN + tid] + bst;
                float spk = (pot >= 1.0f) ? 1.0f : 0.0f;
                pot -= spk;
                cnt += spk;
                so[(size_t)t * DOUT] = spk;
            }
            out[(size_t)NB * T * DOUT + (size_t)n * DOUT + oBase + tid] = cnt;
        }
        __syncthreads();
    }
}

extern "C" void kernel_launch(void* const* d_in, const int* in_sizes, int n_in,
                              void* d_out, int out_size, void* d_ws, size_t ws_size,
                              hipStream_t stream) {
    const float* A     = (const float*)d_in[0];
    // d_in[1] (input_features_sc) feeds only the un-returned ANN path — dead.
    const float* W     = (const float*)d_in[2];
    const float* bias  = (const float*)d_in[3];
    const float* gamma = (const float*)d_in[4];
    const float* beta  = (const float*)d_in[5];
    const float* rmean = (const float*)d_in[6];
    const float* rvar  = (const float*)d_in[7];
    float* out = (float*)d_out;

    if (d_ws != nullptr && ws_size >= WS_BF16) {
        short* Abf = (short*)d_ws;
        short* Wn  = (short*)((char*)d_ws + ABF_BYTES);
        prep_fused<<<PREP_A_BLOCKS + PREP_W_BLOCKS, 256, 0, stream>>>(
            A, Abf, W, gamma, rvar, Wn);
        snn_gemm_if_8ph<<<dim3(512), 512, 0, stream>>>(Abf, Wn, bias, gamma,
                                                       beta, rmean, rvar, out);
    } else if (d_ws != nullptr && ws_size >= WN_BYTES) {
        short* Wn = (short*)d_ws;
        fold_w_kernel<<<DOUT * DIN / 4 / 256, 256, 0, stream>>>(W, gamma, rvar, Wn);
        dim3 grid(DOUT / BN, NB / 2);
        snn_gemm_if<true><<<grid, 256, 0, stream>>>(A, W, Wn, bias, gamma, beta,
                                                    rmean, rvar, out);
    } else {
        dim3 grid(DOUT / BN, NB / 2);
        snn_gemm_if<false><<<grid, 256, 0, stream>>>(A, W, nullptr, bias, gamma, beta,
                                                     rmean, rvar, out);
    }
}